// Round 10
// baseline (672.352 us; speedup 1.0000x reference)
//
#include <hip/hip_runtime.h>

typedef unsigned short u16;
typedef __attribute__((ext_vector_type(8))) short s8v;   // 8 bf16 (4 VGPRs) — MFMA A/B frag
typedef __attribute__((ext_vector_type(4))) float f4v;   // 4 fp32 — MFMA C/D frag

#define NN 16384
#define EE 262144
#define ET (EE + NN)      // 278528 = 4352 * 64
#define NTILES (ET / 64)  // 4352

__device__ __forceinline__ float bfu(u16 h){ return __uint_as_float((unsigned)h << 16); }
__device__ __forceinline__ u16 f2bf(float f){
  unsigned u = __float_as_uint(f);
  unsigned r = u + 0x7FFFu + ((u >> 16) & 1u);   // RNE
  return (u16)(r >> 16);
}
__device__ __forceinline__ float ldf(const void* p, size_t i, int isbf){
  return isbf ? bfu(((const u16*)p)[i]) : ((const float*)p)[i];
}
__device__ __forceinline__ float gelu_f(float x){ return 0.5f*x*(1.0f+erff(x*0.7071067811865475f)); }

__device__ __forceinline__ uint4 load8bf(const void* p, size_t eoff, int isbf){
  if (isbf) return *(const uint4*)((const u16*)p + eoff);
  const float* f = (const float*)p + eoff;
  uint4 r;
  r.x = (unsigned)f2bf(f[0]) | ((unsigned)f2bf(f[1])<<16);
  r.y = (unsigned)f2bf(f[2]) | ((unsigned)f2bf(f[3])<<16);
  r.z = (unsigned)f2bf(f[4]) | ((unsigned)f2bf(f[5])<<16);
  r.w = (unsigned)f2bf(f[6]) | ((unsigned)f2bf(f[7])<<16);
  return r;
}

// async global->LDS, 16B per lane; LDS dest = wave-uniform base + lane*16
__device__ __forceinline__ void gload16(const void* g, void* l){
  __builtin_amdgcn_global_load_lds((const __attribute__((address_space(1))) void*)g,
                                   (__attribute__((address_space(3))) void*)l, 16, 0, 0);
}

// xlr column permutation within a 256-half: c = i*16 + q*4 + r  ->  q*64 + i*4 + r
__device__ __forceinline__ int permc(int c){
  return ((c>>2)&3)*64 + ((c&255)>>4)*4 + (c&3);
}

// ---------------- dtype detector ----------------
__global__ void k_detect(const void* nf, int* flag)
{
  int t = threadIdx.x;
  const float* f = (const float*)nf;
  int cnt = 0;
  for (int i = t; i < 4096; i += 256) {
    float a = fabsf(f[i]);
    if (a > 1e-5f && a < 100.0f) cnt++;   // NaN compares false
  }
  __shared__ int s[256];
  s[t] = cnt; __syncthreads();
  for (int st = 128; st > 0; st >>= 1) { if (t < st) s[t] += s[t+st]; __syncthreads(); }
  if (t == 0) *flag = (s[0] < 2048) ? 1 : 0;
}

// ---------------- generic fp32/bf16 -> bf16 vector convert (8 elems/thread) ----------------
__global__ void k_cvt(const void* __restrict__ in, u16* __restrict__ out, const int* __restrict__ dflag)
{
  int isbf = *dflag;
  size_t i = ((size_t)blockIdx.x*256 + threadIdx.x)*8;
  *(uint4*)&out[i] = load8bf(in, i, isbf);
}

// ---------------- weight convert + concat -> bf16 pool ----------------
__global__ void k_wcvt(const void* __restrict__ lw, const void* __restrict__ rw,
                       const void* __restrict__ w1, const void* __restrict__ w2,
                       const void* __restrict__ iw, u16* __restrict__ wall,
                       const int* __restrict__ dflag)
{
  int isbf = *dflag;
  size_t i = ((size_t)blockIdx.x*256 + threadIdx.x)*8;   // total 983040 elems
  const void* src; size_t off;
  if (i < 196608) { src = iw; off = i; }
  else {
    size_t j = i - 196608;
    size_t l = j / 393216; j -= l*393216;
    if (j < 65536)       { src = lw; off = l*65536 + j; }
    else if (j < 131072) { src = rw; off = l*65536 + (j - 65536); }
    else if (j < 262144) { src = w1; off = l*131072 + (j - 131072); }
    else                 { src = w2; off = l*131072 + (j - 262144); }
  }
  *(uint4*)&wall[i] = load8bf(src, off, isbf);
}

// ---------------- chunk-K GEMM: whole 256-K chunk of A in frag-order LDS, B chunk in regs ----------------
template<int KK, int NJ, int ACT, int CFMT, int PERM>
__global__ __launch_bounds__(256)
void mg4(const u16* __restrict__ A, const u16* __restrict__ B,
         const void* __restrict__ bias1, const void* __restrict__ bias2,
         size_t bioff, int nsplit, int has_bias,
         void* __restrict__ C, void* __restrict__ C2, int N,
         const int* __restrict__ dflag)
{
  __shared__ u16 As[32][512];   // 32 frags (fr = ks*4 + i) x 64 lanes x 8 bf16 = 32 KB
  int isbf = *dflag;
  int t = threadIdx.x;
  int w = t>>6, lane = t&63, l4 = lane&15, quad = lane>>4;

  // XCD-chunked bijective swizzle (nwg = 1024, divisible by 8)
  int nwg = gridDim.x*gridDim.y;
  int wg  = blockIdx.y*gridDim.x + blockIdx.x;
  int lg  = (wg & 7)*(nwg >> 3) + (wg >> 3);
  int bx  = lg % gridDim.x, by = lg / gridDim.x;
  int bm = by*64, bn = bx*(64*NJ);

  const u16* gA = A + (size_t)(bm + w*16 + l4)*KK + quad*8;
  const u16* gB[NJ];
  #pragma unroll
  for (int j=0;j<NJ;++j)
    gB[j] = B + (size_t)(bn + (NJ*w + j)*16 + l4)*KK + quad*8;

  f4v acc[4][NJ];
  f4v zero = {0.f,0.f,0.f,0.f};
  #pragma unroll
  for (int i=0;i<4;++i)
    #pragma unroll
    for (int j=0;j<NJ;++j) acc[i][j] = zero;

  #pragma unroll
  for (int kc=0; kc<KK/256; ++kc) {
    if (kc) __syncthreads();            // prev chunk's LDS reads done
    s8v breg[8][NJ];
    #pragma unroll
    for (int c=0;c<8;++c)
      #pragma unroll
      for (int j=0;j<NJ;++j)
        breg[c][j] = *(const s8v*)(gB[j] + kc*256 + c*32);
    #pragma unroll
    for (int c=0;c<8;++c)
      gload16(gA + kc*256 + c*32, &As[c*4 + w][0]);   // frag (i=w, ks=c)
    __syncthreads();                    // drains gloads + breg loads
    #pragma unroll
    for (int c=0;c<8;++c) {
      s8v a[4];
      #pragma unroll
      for (int i=0;i<4;++i) a[i] = *(const s8v*)&As[c*4 + i][lane*8];
      #pragma unroll
      for (int i=0;i<4;++i)
        #pragma unroll
        for (int j=0;j<NJ;++j)
          acc[i][j] = __builtin_amdgcn_mfma_f32_16x16x32_bf16(a[i], breg[c][j], acc[i][j], 0,0,0);
    }
  }

  // ---- epilogue ----
  #pragma unroll
  for (int i=0;i<4;++i)
    #pragma unroll
    for (int j=0;j<NJ;++j) {
      int cj = bn + (NJ*w + j)*16 + l4;
      float bvs = 0.f;
      if (has_bias) bvs = (cj < nsplit) ? ldf(bias1, bioff + cj, isbf)
                                        : ldf(bias2, bioff + cj - nsplit, isbf);
      int cjs = PERM ? ((cj & ~255) | permc(cj)) : cj;
      #pragma unroll
      for (int r=0;r<4;++r) {
        int row = bm + i*16 + quad*4 + r;
        float v = acc[i][j][r] + bvs;
        if (ACT==1) v = gelu_f(v);
        if (CFMT==1) ((u16*)C)[(size_t)row*N + cjs] = f2bf(v);
        else {
          ((float*)C)[(size_t)row*N + cj] = v;
          if (CFMT==2) ((u16*)C2)[(size_t)row*N + cj] = f2bf(v);
        }
      }
    }
}

// ---------------- CSR build ----------------
__global__ void k_count(const int* __restrict__ dst, int* __restrict__ deg)
{
  int e = blockIdx.x*256 + threadIdx.x;
  if (e >= ET) return;
  int d = (e < EE) ? dst[e] : (e - EE);
  atomicAdd(&deg[d], 1);
}

__global__ void k_scan(const int* __restrict__ deg, int* __restrict__ rowstart)
{
  __shared__ int csum[256];
  int t = threadIdx.x;
  int s = 0;
  for (int i=0;i<64;i++) s += deg[t*64+i];
  csum[t] = s;
  __syncthreads();
  if (t == 0) {
    int r = 0;
    for (int i=0;i<256;i++){ int v = csum[i]; csum[i] = r; r += v; }
    rowstart[NN] = r;
  }
  __syncthreads();
  int b = csum[t];
  for (int i=0;i<64;i++){ rowstart[t*64+i] = b; b += deg[t*64+i]; }
}

// emit src/dst per CSR slot + self-loop slot per node
__global__ void k_scatter(const int* __restrict__ src, const int* __restrict__ dst,
                          const int* __restrict__ rowstart,
                          int* __restrict__ fill, int* __restrict__ csr,
                          int* __restrict__ srcc, int* __restrict__ dstc,
                          int* __restrict__ selfp)
{
  int e = blockIdx.x*256 + threadIdx.x;
  if (e >= ET) return;
  int d  = (e < EE) ? dst[e] : (e - EE);
  int sv = (e < EE) ? src[e] : (e - EE);
  int pos = rowstart[d] + atomicAdd(&fill[d], 1);
  csr[pos]  = e;
  srcc[pos] = sv;
  dstc[pos] = d;
  if (e >= EE) selfp[e - EE] = pos;
}

// ---------------- edge-parallel: gather+convert edge_attr rows into CSR order ----------------
__global__ __launch_bounds__(256)
void k_acsr(const int* __restrict__ csr, const void* __restrict__ edge_attr,
            u16* __restrict__ attr_csr, const int* __restrict__ dflag)
{
  int isbf = *dflag;
  int tid = blockIdx.x*256 + threadIdx.x;   // ET*4 threads exactly
  int pos = tid >> 2, part = tid & 3;
  int eid = csr[pos];                        // broadcast across the 4 threads
  if (eid < EE) {
    uint4 v0 = load8bf(edge_attr, (size_t)eid*64 + part*16,     isbf);
    uint4 v1 = load8bf(edge_attr, (size_t)eid*64 + part*16 + 8, isbf);
    *(uint4*)&attr_csr[(size_t)pos*64 + part*16]     = v0;
    *(uint4*)&attr_csr[(size_t)pos*64 + part*16 + 8] = v1;
  }
}

// ---------------- node-parallel: mean over contiguous CSR segment -> self-loop slot ----------------
__global__ __launch_bounds__(256)
void k_lmean(const int* __restrict__ rowstart, const int* __restrict__ selfp,
             u16* __restrict__ attr_csr)
{
  int j = threadIdx.x & 63, wid = threadIdx.x >> 6;
  int n = blockIdx.x*4 + wid;
  int s = rowstart[n], e1 = rowstart[n+1];
  int sp = selfp[n];
  float sum = 0.f;
  for (int p = s; p < e1; ++p)
    if (p != sp) sum += bfu(attr_csr[(size_t)p*64 + j]);   // sequential 128B/iter
  int cnt = e1 - s - 1;
  attr_csr[(size_t)sp*64 + j] = f2bf(sum / (float)max(cnt, 1));
}

// Wc[l] = lin_edge_w[l] ([256,128]) @ init_edge_w ([128,64]) -> [L,256,64] bf16
__global__ void k_wc(const void* __restrict__ We, const void* __restrict__ iew,
                     u16* __restrict__ Wcb, const int* __restrict__ dflag)
{
  int isbf = *dflag;
  int idx = blockIdx.x*256 + threadIdx.x;    // 32768
  int j = idx & 63, c = (idx >> 6) & 255, l = idx >> 14;
  float s = 0.f;
  for (int k=0;k<128;k++) s += ldf(We, ((size_t)l*256 + c)*128 + k, isbf) * ldf(iew, (size_t)k*64 + j, isbf);
  Wcb[idx] = f2bf(s);
}

// ---------------- edge-parallel logits: interleaved MFMA-pair + epilogue ----------------
__global__ __launch_bounds__(256)
void k_elogits(const int* __restrict__ srcc, const int* __restrict__ dstc,
               const u16* __restrict__ Wcb, const u16* __restrict__ xlr,
               const u16* __restrict__ attr_csr,
               const void* __restrict__ att, size_t att_off,
               float* __restrict__ logits, const int* __restrict__ dflag)
{
  int isbf = *dflag;
  __shared__ u16 WcF[32*64*8];    // 32 A-frags x 64 lanes x 8 bf16 (frag-order, conflict-free b128)
  __shared__ float satt[256];

  int t = threadIdx.x;
  int w = t>>6, lane = t&63, l4 = lane&15, quad = lane>>4;

  satt[t] = ldf(att, att_off + t, isbf);
  #pragma unroll
  for (int f = 0; f < 8; ++f) {
    int fr = w + f*4;              // 0..31
    int i = fr >> 1, ks = fr & 1;
    *(uint4*)&WcF[(fr*64 + lane)*8] = *(const uint4*)&Wcb[(size_t)(16*i + l4)*64 + ks*32 + quad*8];
  }
  __syncthreads();                 // one-time

  f4v zero = {0.f,0.f,0.f,0.f};
  int me = w*16 + l4;
  for (int tile = blockIdx.x; tile < NTILES; tile += gridDim.x) {
    __builtin_amdgcn_sched_barrier(0);   // fence: no cross-tile hoisting/pipelining
    int epos = tile*64 + me;       // this lane's CSR position
    int sn = srcc[epos], dn = dstc[epos];            // 4B broadcast (4 lanes share)
    s8v b0 = *(const s8v*)&attr_csr[(size_t)epos*64 + quad*8];
    s8v b1 = *(const s8v*)&attr_csr[(size_t)epos*64 + 32 + quad*8];

    float ph[8];
    #pragma unroll
    for (int h=0;h<8;++h) ph[h] = 0.f;

    #pragma unroll
    for (int ip=0; ip<8; ++ip){
      int i0 = 2*ip, i1 = 2*ip+1;
      s8v a00 = *(const s8v*)&WcF[((2*i0  )*64 + lane)*8];
      s8v a01 = *(const s8v*)&WcF[((2*i0+1)*64 + lane)*8];
      s8v a10 = *(const s8v*)&WcF[((2*i1  )*64 + lane)*8];
      s8v a11 = *(const s8v*)&WcF[((2*i1+1)*64 + lane)*8];
      f4v acc0 = __builtin_amdgcn_mfma_f32_16x16x32_bf16(a00, b0, zero, 0,0,0);
      acc0     = __builtin_amdgcn_mfma_f32_16x16x32_bf16(a01, b1, acc0, 0,0,0);
      f4v acc1 = __builtin_amdgcn_mfma_f32_16x16x32_bf16(a10, b0, zero, 0,0,0);
      acc1     = __builtin_amdgcn_mfma_f32_16x16x32_bf16(a11, b1, acc1, 0,0,0);
      // permuted xlr: one 16B load covers channels of i0 and i1 for this quad
      uint4 xlv = *(const uint4*)&xlr[(size_t)sn*512 +       quad*64 + ip*8];
      uint4 xrv = *(const uint4*)&xlr[(size_t)dn*512 + 256 + quad*64 + ip*8];
      float4 av0 = *(const float4*)&satt[i0*16 + quad*4];
      float4 av1 = *(const float4*)&satt[i1*16 + quad*4];
      float m0 = acc0[0] + bfu((u16)(xlv.x & 0xffff)) + bfu((u16)(xrv.x & 0xffff));
      float m1 = acc0[1] + bfu((u16)(xlv.x >> 16))    + bfu((u16)(xrv.x >> 16));
      float m2 = acc0[2] + bfu((u16)(xlv.y & 0xffff)) + bfu((u16)(xrv.y & 0xffff));
      float m3 = acc0[3] + bfu((u16)(xlv.y >> 16))    + bfu((u16)(xrv.y >> 16));
      float g0 = fmaxf(m0, 0.2f*m0), g1 = fmaxf(m1, 0.2f*m1);
      float g2 = fmaxf(m2, 0.2f*m2), g3 = fmaxf(m3, 0.2f*m3);
      float s0 = av0.x*g0 + av0.y*g1 + av0.z*g2 + av0.w*g3;
      m0 = acc1[0] + bfu((u16)(xlv.z & 0xffff)) + bfu((u16)(xrv.z & 0xffff));
      m1 = acc1[1] + bfu((u16)(xlv.z >> 16))    + bfu((u16)(xrv.z >> 16));
      m2 = acc1[2] + bfu((u16)(xlv.w & 0xffff)) + bfu((u16)(xrv.w & 0xffff));
      m3 = acc1[3] + bfu((u16)(xlv.w >> 16))    + bfu((u16)(xrv.w >> 16));
      g0 = fmaxf(m0, 0.2f*m0); g1 = fmaxf(m1, 0.2f*m1);
      g2 = fmaxf(m2, 0.2f*m2); g3 = fmaxf(m3, 0.2f*m3);
      ph[ip] = s0 + av1.x*g0 + av1.y*g1 + av1.z*g2 + av1.w*g3;
    }
    #pragma unroll
    for (int h=0;h<8;++h){
      ph[h] += __shfl_xor(ph[h], 16);
      ph[h] += __shfl_xor(ph[h], 32);
    }
    if (quad == 0){
      float4 lo = {ph[0], ph[1], ph[2], ph[3]};
      float4 hi = {ph[4], ph[5], ph[6], ph[7]};
      *(float4*)&logits[(size_t)epos*8]     = lo;
      *(float4*)&logits[(size_t)epos*8 + 4] = hi;
    }
  }
}

// ---------------- per-node segment max + in-place exp of logits ----------------
// one wave per node: lane = (position-offset po, head h). Sequential 256B/iter reads.
__global__ __launch_bounds__(256)
void k_emax(const int* __restrict__ rowstart, float* __restrict__ logits)
{
  int lane = threadIdx.x & 63, wid = threadIdx.x >> 6;
  int n = blockIdx.x*4 + wid;
  int s = rowstart[n], e1 = rowstart[n+1];
  int h = lane & 7, po = lane >> 3;
  float m = -3.0e38f;
  for (int p = s + po; p < e1; p += 8)
    m = fmaxf(m, logits[(size_t)p*8 + h]);
  m = fmaxf(m, __shfl_xor(m, 8));
  m = fmaxf(m, __shfl_xor(m, 16));
  m = fmaxf(m, __shfl_xor(m, 32));     // all lanes now hold max for their head
  for (int p = s + po; p < e1; p += 8) {
    size_t idx = (size_t)p*8 + h;
    logits[idx] = __expf(logits[idx] - m);
  }
}

// ---------------- one wave per node: weighted aggregate (logits pre-exp'd) + bias + residual + LN1 ----------------
// xlr is column-permuted: lane's channels 4*lane..+3 live at (lane&3)*64 + (lane>>2)*4.
// No online softmax: pure FMA accumulation -> loads pipeline freely.
__global__ __launch_bounds__(256)
void k_aggln(const int* __restrict__ srcc, const int* __restrict__ rowstart,
             const float* __restrict__ logits, const u16* __restrict__ xlr, const float* __restrict__ xbuf,
             const void* __restrict__ gat_bias, const void* __restrict__ ln1g, const void* __restrict__ ln1b,
             size_t poff, float* __restrict__ hbuf, u16* __restrict__ hbufb, const int* __restrict__ dflag)
{
  int isbf = *dflag;
  int lane = threadIdx.x & 63, wid = threadIdx.x >> 6;
  int n = blockIdx.x*4 + wid;
  int s = rowstart[n], deg = rowstart[n+1] - s;
  int myh = lane >> 3;                       // head of channels 4*lane..4*lane+3
  int pxl = ((lane&3)<<6) + ((lane>>2)<<2);  // permuted offset of channels 4*lane..+3
  float lrun = 0.f;
  float a0=0.f, a1=0.f, a2=0.f, a3=0.f;

  for (int c0 = 0; c0 < deg; c0 += 64) {
    int idx = s + c0 + lane; if (idx >= ET) idx = ET-1;
    int sv = srcc[idx];
    int lim = min(64, deg - c0);
    size_t lbase = (size_t)(s + c0)*8 + myh;
    for (int j = 0; j < lim; ++j) {
      int sn  = __shfl(sv, j);
      float wv = logits[lbase + (size_t)j*8];        // pre-exponentiated
      uint2 xv = *(const uint2*)&xlr[(size_t)sn*512 + pxl];
      lrun += wv;
      a0 += wv*bfu((u16)(xv.x & 0xffff));
      a1 += wv*bfu((u16)(xv.x >> 16));
      a2 += wv*bfu((u16)(xv.y & 0xffff));
      a3 += wv*bfu((u16)(xv.y >> 16));
    }
  }
  float inv = 1.f/(lrun + 1e-16f);
  int c = 4*lane;
  float4 res = *(const float4*)&xbuf[(size_t)n*256 + c];
  float o0 = a0*inv + ldf(gat_bias, poff+c+0, isbf) + res.x;
  float o1 = a1*inv + ldf(gat_bias, poff+c+1, isbf) + res.y;
  float o2 = a2*inv + ldf(gat_bias, poff+c+2, isbf) + res.z;
  float o3 = a3*inv + ldf(gat_bias, poff+c+3, isbf) + res.w;

  float v = o0+o1+o2+o3;
  #pragma unroll
  for (int off=1; off<64; off<<=1) v += __shfl_xor(v, off);
  float mu = v * (1.f/256.f);
  float d0=o0-mu, d1=o1-mu, d2=o2-mu, d3=o3-mu;
  float v2 = d0*d0+d1*d1+d2*d2+d3*d3;
  #pragma unroll
  for (int off=1; off<64; off<<=1) v2 += __shfl_xor(v2, off);
  float wn = rsqrtf(v2*(1.f/256.f) + 1e-5f);
  float4 outv;
  outv.x = d0*wn*ldf(ln1g, poff+c+0, isbf) + ldf(ln1b, poff+c+0, isbf);
  outv.y = d1*wn*ldf(ln1g, poff+c+1, isbf) + ldf(ln1b, poff+c+1, isbf);
  outv.z = d2*wn*ldf(ln1g, poff+c+2, isbf) + ldf(ln1b, poff+c+2, isbf);
  outv.w = d3*wn*ldf(ln1g, poff+c+3, isbf) + ldf(ln1b, poff+c+3, isbf);
  *(float4*)&hbuf[(size_t)n*256 + c] = outv;
  uint2 hb;
  hb.x = (unsigned)f2bf(outv.x) | ((unsigned)f2bf(outv.y)<<16);
  hb.y = (unsigned)f2bf(outv.z) | ((unsigned)f2bf(outv.w)<<16);
  *(uint2*)&hbufb[(size_t)n*256 + c] = hb;
}

// ---------------- residual + LN2 -> xbuf (fp32 + bf16) ----------------
__global__ __launch_bounds__(256)
void k_ln_add(const float* __restrict__ a, const u16* __restrict__ b2,
              const void* __restrict__ gg, const void* __restrict__ bb, size_t poff,
              float* __restrict__ out, u16* __restrict__ outb, const int* __restrict__ dflag)
{
  int isbf = *dflag;
  int n = blockIdx.x, t = threadIdx.x;
  __shared__ float r[256];
  float x = a[(size_t)n*256 + t] + bfu(b2[(size_t)n*256 + t]);
  r[t] = x; __syncthreads();
  for (int st = 128; st > 0; st >>= 1) { if (t < st) r[t] += r[t+st]; __syncthreads(); }
  float mu = r[0] * (1.f/256.f);
  __syncthreads();
  float d = x - mu;
  r[t] = d*d; __syncthreads();
  for (int st = 128; st > 0; st >>= 1) { if (t < st) r[t] += r[t+st]; __syncthreads(); }
  float var = r[0] * (1.f/256.f);
  float o = d * rsqrtf(var + 1e-5f) * ldf(gg, poff + t, isbf) + ldf(bb, poff + t, isbf);
  out[(size_t)n*256 + t] = o;
  outb[(size_t)n*256 + t] = f2bf(o);
}

__global__ void k_out(const float* __restrict__ x, void* __restrict__ out, const int* __restrict__ dflag)
{
  int isbf = *dflag;
  int i = blockIdx.x*256 + threadIdx.x;
  if (isbf) ((u16*)out)[i] = f2bf(x[i]);
  else      ((float*)out)[i] = x[i];
}

extern "C" void kernel_launch(void* const* d_in, const int* in_sizes, int n_in,
                              void* d_out, int out_size, void* d_ws, size_t ws_size,
                              hipStream_t stream)
{
  const void* node_feats = d_in[0];
  const int*  edge_index = (const int*)d_in[1];
  const void* edge_attr  = d_in[2];
  const void* init_node_w= d_in[3];
  const void* init_edge_w= d_in[4];
  const void* lin_l_w    = d_in[5];
  const void* lin_l_b    = d_in[6];
  const void* lin_r_w    = d_in[7];
  const void* lin_r_b    = d_in[8];
  const void* lin_edge_w = d_in[9];
  const void* att        = d_in[10];
  const void* gat_bias   = d_in[11];
  const void* ln1_g      = d_in[12];
  const void* ln1_b      = d_in[13];
  const void* mlp_w1     = d_in[14];
  const void* mlp_w2     = d_in[15];
  const void* ln2_g      = d_in[16];
  const void* ln2_b      = d_in[17];

  const int* srcp = edge_index;
  const int* dstp = edge_index + EE;

  char* p = (char*)d_ws;
  auto alloc = [&](size_t bytes) { void* r = (void*)p; p += (bytes + 255) & ~(size_t)255; return r; };
  int*   dflag   = (int*)alloc(256);
  int*   deg     = (int*)alloc((size_t)NN*4);
  int*   rowstart= (int*)alloc((size_t)(NN+1)*4);
  int*   fill    = (int*)alloc((size_t)NN*4);
  int*   csr     = (int*)alloc((size_t)ET*4);
  int*   srcc    = (int*)alloc((size_t)ET*4);
  int*   dstc    = (int*)alloc((size_t)ET*4);
  int*   selfp   = (int*)alloc((size_t)NN*4);
  u16*   Wcb     = (u16*)alloc((size_t)2*256*64*2);
  u16*   wall    = (u16*)alloc((size_t)983040*2);   // bf16 weight pool
  u16*   attr_csr= (u16*)alloc((size_t)ET*64*2);    // 35.6 MB, CSR-ordered bf16 edge attrs
  float* logits  = (float*)alloc((size_t)ET*8*4);           // 8.9 MB
  float* hbuf    = (float*)alloc((size_t)NN*256*4);         // 16 MB
  float* xbuf    = (float*)alloc((size_t)NN*256*4);         // 16 MB
  u16*   xbufb   = (u16*)alloc((size_t)NN*256*2);
  u16*   hbufb   = (u16*)alloc((size_t)NN*256*2);
  u16*   xlr     = (u16*)alloc((size_t)NN*512*2);  // PERMUTED cols: xl 0..255, xr 256..511
  u16*   nfb     = (u16*)logits;    // dead before logits/hbuf are written
  u16*   ymid    = xlr;             // [NN,512] bf16 alias (xlr dead at MLP time; linear layout)
  u16*   y2      = (u16*)d_out;     // bf16 scratch; final k_out overwrites

  u16* Wn = wall;                   // [256][768]

  hipMemsetAsync(deg,  0, (size_t)NN*4, stream);
  hipMemsetAsync(fill, 0, (size_t)NN*4, stream);

  k_detect <<<1, 256, 0, stream>>>(node_feats, dflag);

  k_count  <<<(ET+255)/256, 256, 0, stream>>>(dstp, deg);
  k_scan   <<<1, 256, 0, stream>>>(deg, rowstart);
  k_scatter<<<(ET+255)/256, 256, 0, stream>>>(srcp, dstp, rowstart, fill, csr, srcc, dstc, selfp);
  // edge-parallel attr reorder (convert), then sequential-segment mean into self slots
  k_acsr   <<<(ET*4)/256, 256, 0, stream>>>(csr, edge_attr, attr_csr, dflag);
  k_lmean  <<<NN/4, 256, 0, stream>>>(rowstart, selfp, attr_csr);

  k_wc     <<<128, 256, 0, stream>>>(lin_edge_w, init_edge_w, Wcb, dflag);
  k_wcvt   <<<480, 256, 0, stream>>>(lin_l_w, lin_r_w, mlp_w1, mlp_w2, init_node_w, wall, dflag);

  // node_feats -> bf16
  k_cvt<<<(NN*768)/(8*256), 256, 0, stream>>>(node_feats, nfb, dflag);
  // x = node_feats @ init_node_w.T  (fp32 xbuf + bf16 xbufb)
  mg4<768,1,0,2,0><<<dim3(4, NN/64), 256, 0, stream>>>(nfb, Wn, nullptr, nullptr, 0, 1<<29, 0,
                                                       xbuf, xbufb, 256, dflag);

  for (int l = 0; l < 2; ++l) {
    size_t bo = (size_t)l*256;
    u16* Wlr = wall + 196608 + (size_t)l*393216;   // [512][256]: rows 0-255 lin_l, 256-511 lin_r
    u16* W1  = Wlr + 131072;                       // [512][256]
    u16* W2  = Wlr + 262144;                       // [256][512]
    // xlr = [x@Wl^T + bl | x@Wr^T + br]  (PERMUTED column layout)
    mg4<256,2,0,1,1><<<dim3(4, NN/64), 256, 0, stream>>>(xbufb, Wlr, lin_l_b, lin_r_b, bo, 256, 1,
                                                         xlr, nullptr, 512, dflag);
    k_elogits<<<1024, 256, 0, stream>>>(srcc, dstc, Wcb + (size_t)l*256*64, xlr,
                                        attr_csr, att, (size_t)l*256, logits, dflag);
    k_emax   <<<NN/4, 256, 0, stream>>>(rowstart, logits);
    k_aggln  <<<NN/4, 256, 0, stream>>>(srcc, rowstart, logits, xlr, xbuf,
                                        gat_bias, ln1_g, ln1_b, bo, hbuf, hbufb, dflag);
    mg4<256,2,1,1,0><<<dim3(4, NN/64), 256, 0, stream>>>(hbufb, W1, nullptr, nullptr, 0, 1<<29, 0,
                                                         ymid, nullptr, 512, dflag);
    mg4<512,1,0,1,0><<<dim3(4, NN/64), 256, 0, stream>>>(ymid, W2, nullptr, nullptr, 0, 1<<29, 0,
                                                         y2, nullptr, 256, dflag);
    k_ln_add<<<NN, 256, 0, stream>>>(hbuf, y2, ln2_g, ln2_b, bo, xbuf, xbufb, dflag);
  }

  k_out<<<(NN*256)/256, 256, 0, stream>>>(xbuf, d_out, dflag);
}

// Round 11
// 656.986 us; speedup vs baseline: 1.0234x; 1.0234x over previous
//
#include <hip/hip_runtime.h>

typedef unsigned short u16;
typedef __attribute__((ext_vector_type(8))) short s8v;   // 8 bf16 (4 VGPRs) — MFMA A/B frag
typedef __attribute__((ext_vector_type(4))) float f4v;   // 4 fp32 — MFMA C/D frag

#define NN 16384
#define EE 262144
#define ET (EE + NN)      // 278528 = 4352 * 64
#define NTILES (ET / 64)  // 4352

__device__ __forceinline__ float bfu(u16 h){ return __uint_as_float((unsigned)h << 16); }
__device__ __forceinline__ u16 f2bf(float f){
  unsigned u = __float_as_uint(f);
  unsigned r = u + 0x7FFFu + ((u >> 16) & 1u);   // RNE
  return (u16)(r >> 16);
}
__device__ __forceinline__ float ldf(const void* p, size_t i, int isbf){
  return isbf ? bfu(((const u16*)p)[i]) : ((const float*)p)[i];
}
__device__ __forceinline__ float gelu_f(float x){ return 0.5f*x*(1.0f+erff(x*0.7071067811865475f)); }

__device__ __forceinline__ uint4 load8bf(const void* p, size_t eoff, int isbf){
  if (isbf) return *(const uint4*)((const u16*)p + eoff);
  const float* f = (const float*)p + eoff;
  uint4 r;
  r.x = (unsigned)f2bf(f[0]) | ((unsigned)f2bf(f[1])<<16);
  r.y = (unsigned)f2bf(f[2]) | ((unsigned)f2bf(f[3])<<16);
  r.z = (unsigned)f2bf(f[4]) | ((unsigned)f2bf(f[5])<<16);
  r.w = (unsigned)f2bf(f[6]) | ((unsigned)f2bf(f[7])<<16);
  return r;
}

// async global->LDS, 16B per lane; LDS dest = wave-uniform base + lane*16
__device__ __forceinline__ void gload16(const void* g, void* l){
  __builtin_amdgcn_global_load_lds((const __attribute__((address_space(1))) void*)g,
                                   (__attribute__((address_space(3))) void*)l, 16, 0, 0);
}

// xlr column permutation within a 256-half: c = i*16 + q*4 + r  ->  q*64 + i*4 + r
__device__ __forceinline__ int permc(int c){
  return ((c>>2)&3)*64 + ((c&255)>>4)*4 + (c&3);
}

// ---------------- dtype detector ----------------
__global__ void k_detect(const void* nf, int* flag)
{
  int t = threadIdx.x;
  const float* f = (const float*)nf;
  int cnt = 0;
  for (int i = t; i < 4096; i += 256) {
    float a = fabsf(f[i]);
    if (a > 1e-5f && a < 100.0f) cnt++;   // NaN compares false
  }
  __shared__ int s[256];
  s[t] = cnt; __syncthreads();
  for (int st = 128; st > 0; st >>= 1) { if (t < st) s[t] += s[t+st]; __syncthreads(); }
  if (t == 0) *flag = (s[0] < 2048) ? 1 : 0;
}

// ---------------- generic fp32/bf16 -> bf16 vector convert (8 elems/thread) ----------------
__global__ void k_cvt(const void* __restrict__ in, u16* __restrict__ out, const int* __restrict__ dflag)
{
  int isbf = *dflag;
  size_t i = ((size_t)blockIdx.x*256 + threadIdx.x)*8;
  *(uint4*)&out[i] = load8bf(in, i, isbf);
}

// ---------------- weight convert + concat -> bf16 pool ----------------
__global__ void k_wcvt(const void* __restrict__ lw, const void* __restrict__ rw,
                       const void* __restrict__ w1, const void* __restrict__ w2,
                       const void* __restrict__ iw, u16* __restrict__ wall,
                       const int* __restrict__ dflag)
{
  int isbf = *dflag;
  size_t i = ((size_t)blockIdx.x*256 + threadIdx.x)*8;   // total 983040 elems
  const void* src; size_t off;
  if (i < 196608) { src = iw; off = i; }
  else {
    size_t j = i - 196608;
    size_t l = j / 393216; j -= l*393216;
    if (j < 65536)       { src = lw; off = l*65536 + j; }
    else if (j < 131072) { src = rw; off = l*65536 + (j - 65536); }
    else if (j < 262144) { src = w1; off = l*131072 + (j - 131072); }
    else                 { src = w2; off = l*131072 + (j - 262144); }
  }
  *(uint4*)&wall[i] = load8bf(src, off, isbf);
}

// ---------------- chunk-K GEMM: whole 256-K chunk of A in frag-order LDS, B chunk in regs ----------------
template<int KK, int NJ, int ACT, int CFMT, int PERM>
__global__ __launch_bounds__(256)
void mg4(const u16* __restrict__ A, const u16* __restrict__ B,
         const void* __restrict__ bias1, const void* __restrict__ bias2,
         size_t bioff, int nsplit, int has_bias,
         void* __restrict__ C, void* __restrict__ C2, int N,
         const int* __restrict__ dflag)
{
  __shared__ u16 As[32][512];   // 32 frags (fr = ks*4 + i) x 64 lanes x 8 bf16 = 32 KB
  int isbf = *dflag;
  int t = threadIdx.x;
  int w = t>>6, lane = t&63, l4 = lane&15, quad = lane>>4;

  // XCD-chunked bijective swizzle (nwg = 1024, divisible by 8)
  int nwg = gridDim.x*gridDim.y;
  int wg  = blockIdx.y*gridDim.x + blockIdx.x;
  int lg  = (wg & 7)*(nwg >> 3) + (wg >> 3);
  int bx  = lg % gridDim.x, by = lg / gridDim.x;
  int bm = by*64, bn = bx*(64*NJ);

  const u16* gA = A + (size_t)(bm + w*16 + l4)*KK + quad*8;
  const u16* gB[NJ];
  #pragma unroll
  for (int j=0;j<NJ;++j)
    gB[j] = B + (size_t)(bn + (NJ*w + j)*16 + l4)*KK + quad*8;

  f4v acc[4][NJ];
  f4v zero = {0.f,0.f,0.f,0.f};
  #pragma unroll
  for (int i=0;i<4;++i)
    #pragma unroll
    for (int j=0;j<NJ;++j) acc[i][j] = zero;

  #pragma unroll
  for (int kc=0; kc<KK/256; ++kc) {
    if (kc) __syncthreads();            // prev chunk's LDS reads done
    s8v breg[8][NJ];
    #pragma unroll
    for (int c=0;c<8;++c)
      #pragma unroll
      for (int j=0;j<NJ;++j)
        breg[c][j] = *(const s8v*)(gB[j] + kc*256 + c*32);
    #pragma unroll
    for (int c=0;c<8;++c)
      gload16(gA + kc*256 + c*32, &As[c*4 + w][0]);   // frag (i=w, ks=c)
    __syncthreads();                    // drains gloads + breg loads
    #pragma unroll
    for (int c=0;c<8;++c) {
      s8v a[4];
      #pragma unroll
      for (int i=0;i<4;++i) a[i] = *(const s8v*)&As[c*4 + i][lane*8];
      #pragma unroll
      for (int i=0;i<4;++i)
        #pragma unroll
        for (int j=0;j<NJ;++j)
          acc[i][j] = __builtin_amdgcn_mfma_f32_16x16x32_bf16(a[i], breg[c][j], acc[i][j], 0,0,0);
    }
  }

  // ---- epilogue ----
  #pragma unroll
  for (int i=0;i<4;++i)
    #pragma unroll
    for (int j=0;j<NJ;++j) {
      int cj = bn + (NJ*w + j)*16 + l4;
      float bvs = 0.f;
      if (has_bias) bvs = (cj < nsplit) ? ldf(bias1, bioff + cj, isbf)
                                        : ldf(bias2, bioff + cj - nsplit, isbf);
      int cjs = PERM ? ((cj & ~255) | permc(cj)) : cj;
      #pragma unroll
      for (int r=0;r<4;++r) {
        int row = bm + i*16 + quad*4 + r;
        float v = acc[i][j][r] + bvs;
        if (ACT==1) v = gelu_f(v);
        if (CFMT==1) ((u16*)C)[(size_t)row*N + cjs] = f2bf(v);
        else {
          ((float*)C)[(size_t)row*N + cj] = v;
          if (CFMT==2) ((u16*)C2)[(size_t)row*N + cj] = f2bf(v);
        }
      }
    }
}

// ---------------- CSR build ----------------
__global__ void k_count(const int* __restrict__ dst, int* __restrict__ deg)
{
  int e = blockIdx.x*256 + threadIdx.x;
  if (e >= ET) return;
  int d = (e < EE) ? dst[e] : (e - EE);
  atomicAdd(&deg[d], 1);
}

__global__ void k_scan(const int* __restrict__ deg, int* __restrict__ rowstart)
{
  __shared__ int csum[256];
  int t = threadIdx.x;
  int s = 0;
  for (int i=0;i<64;i++) s += deg[t*64+i];
  csum[t] = s;
  __syncthreads();
  if (t == 0) {
    int r = 0;
    for (int i=0;i<256;i++){ int v = csum[i]; csum[i] = r; r += v; }
    rowstart[NN] = r;
  }
  __syncthreads();
  int b = csum[t];
  for (int i=0;i<64;i++){ rowstart[t*64+i] = b; b += deg[t*64+i]; }
}

// emit src/dst per CSR slot + self-loop slot per node
__global__ void k_scatter(const int* __restrict__ src, const int* __restrict__ dst,
                          const int* __restrict__ rowstart,
                          int* __restrict__ fill, int* __restrict__ csr,
                          int* __restrict__ srcc, int* __restrict__ dstc,
                          int* __restrict__ selfp)
{
  int e = blockIdx.x*256 + threadIdx.x;
  if (e >= ET) return;
  int d  = (e < EE) ? dst[e] : (e - EE);
  int sv = (e < EE) ? src[e] : (e - EE);
  int pos = rowstart[d] + atomicAdd(&fill[d], 1);
  csr[pos]  = e;
  srcc[pos] = sv;
  dstc[pos] = d;
  if (e >= EE) selfp[e - EE] = pos;
}

// ---------------- edge-parallel: gather+convert edge_attr rows into CSR order ----------------
__global__ __launch_bounds__(256)
void k_acsr(const int* __restrict__ csr, const void* __restrict__ edge_attr,
            u16* __restrict__ attr_csr, const int* __restrict__ dflag)
{
  int isbf = *dflag;
  int tid = blockIdx.x*256 + threadIdx.x;   // ET*4 threads exactly
  int pos = tid >> 2, part = tid & 3;
  int eid = csr[pos];                        // broadcast across the 4 threads
  if (eid < EE) {
    uint4 v0 = load8bf(edge_attr, (size_t)eid*64 + part*16,     isbf);
    uint4 v1 = load8bf(edge_attr, (size_t)eid*64 + part*16 + 8, isbf);
    *(uint4*)&attr_csr[(size_t)pos*64 + part*16]     = v0;
    *(uint4*)&attr_csr[(size_t)pos*64 + part*16 + 8] = v1;
  }
}

// ---------------- node-parallel: mean over contiguous CSR segment -> self-loop slot ----------------
__global__ __launch_bounds__(256)
void k_lmean(const int* __restrict__ rowstart, const int* __restrict__ selfp,
             u16* __restrict__ attr_csr)
{
  int j = threadIdx.x & 63, wid = threadIdx.x >> 6;
  int n = blockIdx.x*4 + wid;
  int s = rowstart[n], e1 = rowstart[n+1];
  int sp = selfp[n];
  float sum = 0.f;
  for (int p = s; p < e1; ++p)
    if (p != sp) sum += bfu(attr_csr[(size_t)p*64 + j]);   // sequential 128B/iter
  int cnt = e1 - s - 1;
  attr_csr[(size_t)sp*64 + j] = f2bf(sum / (float)max(cnt, 1));
}

// Wc[l] = lin_edge_w[l] ([256,128]) @ init_edge_w ([128,64]) -> [L,256,64] bf16
__global__ void k_wc(const void* __restrict__ We, const void* __restrict__ iew,
                     u16* __restrict__ Wcb, const int* __restrict__ dflag)
{
  int isbf = *dflag;
  int idx = blockIdx.x*256 + threadIdx.x;    // 32768
  int j = idx & 63, c = (idx >> 6) & 255, l = idx >> 14;
  float s = 0.f;
  for (int k=0;k<128;k++) s += ldf(We, ((size_t)l*256 + c)*128 + k, isbf) * ldf(iew, (size_t)k*64 + j, isbf);
  Wcb[idx] = f2bf(s);
}

// ---------------- edge-parallel logits: interleaved MFMA-pair + epilogue ----------------
__global__ __launch_bounds__(256)
void k_elogits(const int* __restrict__ srcc, const int* __restrict__ dstc,
               const u16* __restrict__ Wcb, const u16* __restrict__ xlr,
               const u16* __restrict__ attr_csr,
               const void* __restrict__ att, size_t att_off,
               float* __restrict__ logits, const int* __restrict__ dflag)
{
  int isbf = *dflag;
  __shared__ u16 WcF[32*64*8];    // 32 A-frags x 64 lanes x 8 bf16 (frag-order, conflict-free b128)
  __shared__ float satt[256];

  int t = threadIdx.x;
  int w = t>>6, lane = t&63, l4 = lane&15, quad = lane>>4;

  satt[t] = ldf(att, att_off + t, isbf);
  #pragma unroll
  for (int f = 0; f < 8; ++f) {
    int fr = w + f*4;              // 0..31
    int i = fr >> 1, ks = fr & 1;
    *(uint4*)&WcF[(fr*64 + lane)*8] = *(const uint4*)&Wcb[(size_t)(16*i + l4)*64 + ks*32 + quad*8];
  }
  __syncthreads();                 // one-time

  f4v zero = {0.f,0.f,0.f,0.f};
  int me = w*16 + l4;
  for (int tile = blockIdx.x; tile < NTILES; tile += gridDim.x) {
    __builtin_amdgcn_sched_barrier(0);   // fence: no cross-tile hoisting/pipelining
    int epos = tile*64 + me;       // this lane's CSR position
    int sn = srcc[epos], dn = dstc[epos];            // 4B broadcast (4 lanes share)
    s8v b0 = *(const s8v*)&attr_csr[(size_t)epos*64 + quad*8];
    s8v b1 = *(const s8v*)&attr_csr[(size_t)epos*64 + 32 + quad*8];

    float ph[8];
    #pragma unroll
    for (int h=0;h<8;++h) ph[h] = 0.f;

    #pragma unroll
    for (int ip=0; ip<8; ++ip){
      int i0 = 2*ip, i1 = 2*ip+1;
      s8v a00 = *(const s8v*)&WcF[((2*i0  )*64 + lane)*8];
      s8v a01 = *(const s8v*)&WcF[((2*i0+1)*64 + lane)*8];
      s8v a10 = *(const s8v*)&WcF[((2*i1  )*64 + lane)*8];
      s8v a11 = *(const s8v*)&WcF[((2*i1+1)*64 + lane)*8];
      f4v acc0 = __builtin_amdgcn_mfma_f32_16x16x32_bf16(a00, b0, zero, 0,0,0);
      acc0     = __builtin_amdgcn_mfma_f32_16x16x32_bf16(a01, b1, acc0, 0,0,0);
      f4v acc1 = __builtin_amdgcn_mfma_f32_16x16x32_bf16(a10, b0, zero, 0,0,0);
      acc1     = __builtin_amdgcn_mfma_f32_16x16x32_bf16(a11, b1, acc1, 0,0,0);
      // permuted xlr: one 16B load covers channels of i0 and i1 for this quad
      uint4 xlv = *(const uint4*)&xlr[(size_t)sn*512 +       quad*64 + ip*8];
      uint4 xrv = *(const uint4*)&xlr[(size_t)dn*512 + 256 + quad*64 + ip*8];
      float4 av0 = *(const float4*)&satt[i0*16 + quad*4];
      float4 av1 = *(const float4*)&satt[i1*16 + quad*4];
      float m0 = acc0[0] + bfu((u16)(xlv.x & 0xffff)) + bfu((u16)(xrv.x & 0xffff));
      float m1 = acc0[1] + bfu((u16)(xlv.x >> 16))    + bfu((u16)(xrv.x >> 16));
      float m2 = acc0[2] + bfu((u16)(xlv.y & 0xffff)) + bfu((u16)(xrv.y & 0xffff));
      float m3 = acc0[3] + bfu((u16)(xlv.y >> 16))    + bfu((u16)(xrv.y >> 16));
      float g0 = fmaxf(m0, 0.2f*m0), g1 = fmaxf(m1, 0.2f*m1);
      float g2 = fmaxf(m2, 0.2f*m2), g3 = fmaxf(m3, 0.2f*m3);
      float s0 = av0.x*g0 + av0.y*g1 + av0.z*g2 + av0.w*g3;
      m0 = acc1[0] + bfu((u16)(xlv.z & 0xffff)) + bfu((u16)(xrv.z & 0xffff));
      m1 = acc1[1] + bfu((u16)(xlv.z >> 16))    + bfu((u16)(xrv.z >> 16));
      m2 = acc1[2] + bfu((u16)(xlv.w & 0xffff)) + bfu((u16)(xrv.w & 0xffff));
      m3 = acc1[3] + bfu((u16)(xlv.w >> 16))    + bfu((u16)(xrv.w >> 16));
      g0 = fmaxf(m0, 0.2f*m0); g1 = fmaxf(m1, 0.2f*m1);
      g2 = fmaxf(m2, 0.2f*m2); g3 = fmaxf(m3, 0.2f*m3);
      ph[ip] = s0 + av1.x*g0 + av1.y*g1 + av1.z*g2 + av1.w*g3;
    }
    #pragma unroll
    for (int h=0;h<8;++h){
      ph[h] += __shfl_xor(ph[h], 16);
      ph[h] += __shfl_xor(ph[h], 32);
    }
    if (quad == 0){
      float4 lo = {ph[0], ph[1], ph[2], ph[3]};
      float4 hi = {ph[4], ph[5], ph[6], ph[7]};
      *(float4*)&logits[(size_t)epos*8]     = lo;
      *(float4*)&logits[(size_t)epos*8 + 4] = hi;
    }
  }
}

// ---------------- one wave per node: seg-max pass + weighted aggregate + bias + residual + LN1 ----------------
// xlr is column-permuted: lane's channels 4*lane..+3 live at (lane&3)*64 + (lane>>2)*4.
// Pass 1 computes per-head max (sequential reads); pass 2 is 4x-unrolled with batched
// independent gathers (4 xv loads in flight) and inline exp (not loop-carried).
__global__ __launch_bounds__(256)
void k_aggln(const int* __restrict__ srcc, const int* __restrict__ rowstart,
             const float* __restrict__ logits, const u16* __restrict__ xlr, const float* __restrict__ xbuf,
             const void* __restrict__ gat_bias, const void* __restrict__ ln1g, const void* __restrict__ ln1b,
             size_t poff, float* __restrict__ hbuf, u16* __restrict__ hbufb, const int* __restrict__ dflag)
{
  int isbf = *dflag;
  int lane = threadIdx.x & 63, wid = threadIdx.x >> 6;
  int n = blockIdx.x*4 + wid;
  int s = rowstart[n], deg = rowstart[n+1] - s;
  int myh = lane >> 3;                       // head of channels 4*lane..4*lane+3
  int pxl = ((lane&3)<<6) + ((lane>>2)<<2);  // permuted offset of channels 4*lane..+3

  // ---- pass 1: per-head segment max (k_emax layout: h = lane&7, po = lane>>3) ----
  {
    int h = lane & 7, po = lane >> 3;
    float m = -3.0e38f;
    for (int p = s + po; p < s + deg; p += 8)
      m = fmaxf(m, logits[(size_t)p*8 + h]);
    m = fmaxf(m, __shfl_xor(m, 8));
    m = fmaxf(m, __shfl_xor(m, 16));
    m = fmaxf(m, __shfl_xor(m, 32));       // lane L holds max for head L&7
    float mh = __shfl(m, myh);             // max for this lane's head
    // ---- pass 2: aggregate ----
    float lrun = 0.f;
    float a0=0.f, a1=0.f, a2=0.f, a3=0.f;
    for (int c0 = 0; c0 < deg; c0 += 64) {
      int idx = s + c0 + lane; if (idx >= ET) idx = ET-1;
      int sv = srcc[idx];
      int lim = min(64, deg - c0);
      size_t lbase = (size_t)(s + c0)*8 + myh;
      int j = 0;
      for (; j + 4 <= lim; j += 4) {
        int sn0 = __shfl(sv, j), sn1 = __shfl(sv, j+1);
        int sn2 = __shfl(sv, j+2), sn3 = __shfl(sv, j+3);
        float lg0 = logits[lbase + (size_t)(j  )*8];
        float lg1 = logits[lbase + (size_t)(j+1)*8];
        float lg2 = logits[lbase + (size_t)(j+2)*8];
        float lg3 = logits[lbase + (size_t)(j+3)*8];
        uint2 xv0 = *(const uint2*)&xlr[(size_t)sn0*512 + pxl];
        uint2 xv1 = *(const uint2*)&xlr[(size_t)sn1*512 + pxl];
        uint2 xv2 = *(const uint2*)&xlr[(size_t)sn2*512 + pxl];
        uint2 xv3 = *(const uint2*)&xlr[(size_t)sn3*512 + pxl];
        float w0 = __expf(lg0 - mh), w1 = __expf(lg1 - mh);
        float w2 = __expf(lg2 - mh), w3 = __expf(lg3 - mh);
        lrun += (w0 + w1) + (w2 + w3);
        a0 += w0*bfu((u16)(xv0.x & 0xffff)) + w1*bfu((u16)(xv1.x & 0xffff))
            + w2*bfu((u16)(xv2.x & 0xffff)) + w3*bfu((u16)(xv3.x & 0xffff));
        a1 += w0*bfu((u16)(xv0.x >> 16))    + w1*bfu((u16)(xv1.x >> 16))
            + w2*bfu((u16)(xv2.x >> 16))    + w3*bfu((u16)(xv3.x >> 16));
        a2 += w0*bfu((u16)(xv0.y & 0xffff)) + w1*bfu((u16)(xv1.y & 0xffff))
            + w2*bfu((u16)(xv2.y & 0xffff)) + w3*bfu((u16)(xv3.y & 0xffff));
        a3 += w0*bfu((u16)(xv0.y >> 16))    + w1*bfu((u16)(xv1.y >> 16))
            + w2*bfu((u16)(xv2.y >> 16))    + w3*bfu((u16)(xv3.y >> 16));
      }
      for (; j < lim; ++j) {
        int sn  = __shfl(sv, j);
        float wv = __expf(logits[lbase + (size_t)j*8] - mh);
        uint2 xv = *(const uint2*)&xlr[(size_t)sn*512 + pxl];
        lrun += wv;
        a0 += wv*bfu((u16)(xv.x & 0xffff));
        a1 += wv*bfu((u16)(xv.x >> 16));
        a2 += wv*bfu((u16)(xv.y & 0xffff));
        a3 += wv*bfu((u16)(xv.y >> 16));
      }
    }
    float inv = 1.f/(lrun + 1e-16f);
    int c = 4*lane;
    float4 res = *(const float4*)&xbuf[(size_t)n*256 + c];
    float o0 = a0*inv + ldf(gat_bias, poff+c+0, isbf) + res.x;
    float o1 = a1*inv + ldf(gat_bias, poff+c+1, isbf) + res.y;
    float o2 = a2*inv + ldf(gat_bias, poff+c+2, isbf) + res.z;
    float o3 = a3*inv + ldf(gat_bias, poff+c+3, isbf) + res.w;

    float v = o0+o1+o2+o3;
    #pragma unroll
    for (int off=1; off<64; off<<=1) v += __shfl_xor(v, off);
    float mu = v * (1.f/256.f);
    float d0=o0-mu, d1=o1-mu, d2=o2-mu, d3=o3-mu;
    float v2 = d0*d0+d1*d1+d2*d2+d3*d3;
    #pragma unroll
    for (int off=1; off<64; off<<=1) v2 += __shfl_xor(v2, off);
    float wn = rsqrtf(v2*(1.f/256.f) + 1e-5f);
    float4 outv;
    outv.x = d0*wn*ldf(ln1g, poff+c+0, isbf) + ldf(ln1b, poff+c+0, isbf);
    outv.y = d1*wn*ldf(ln1g, poff+c+1, isbf) + ldf(ln1b, poff+c+1, isbf);
    outv.z = d2*wn*ldf(ln1g, poff+c+2, isbf) + ldf(ln1b, poff+c+2, isbf);
    outv.w = d3*wn*ldf(ln1g, poff+c+3, isbf) + ldf(ln1b, poff+c+3, isbf);
    *(float4*)&hbuf[(size_t)n*256 + c] = outv;
    uint2 hb;
    hb.x = (unsigned)f2bf(outv.x) | ((unsigned)f2bf(outv.y)<<16);
    hb.y = (unsigned)f2bf(outv.z) | ((unsigned)f2bf(outv.w)<<16);
    *(uint2*)&hbufb[(size_t)n*256 + c] = hb;
  }
}

// ---------------- residual + LN2 -> xbuf (fp32 + bf16) ----------------
__global__ __launch_bounds__(256)
void k_ln_add(const float* __restrict__ a, const u16* __restrict__ b2,
              const void* __restrict__ gg, const void* __restrict__ bb, size_t poff,
              float* __restrict__ out, u16* __restrict__ outb, const int* __restrict__ dflag)
{
  int isbf = *dflag;
  int n = blockIdx.x, t = threadIdx.x;
  __shared__ float r[256];
  float x = a[(size_t)n*256 + t] + bfu(b2[(size_t)n*256 + t]);
  r[t] = x; __syncthreads();
  for (int st = 128; st > 0; st >>= 1) { if (t < st) r[t] += r[t+st]; __syncthreads(); }
  float mu = r[0] * (1.f/256.f);
  __syncthreads();
  float d = x - mu;
  r[t] = d*d; __syncthreads();
  for (int st = 128; st > 0; st >>= 1) { if (t < st) r[t] += r[t+st]; __syncthreads(); }
  float var = r[0] * (1.f/256.f);
  float o = d * rsqrtf(var + 1e-5f) * ldf(gg, poff + t, isbf) + ldf(bb, poff + t, isbf);
  out[(size_t)n*256 + t] = o;
  outb[(size_t)n*256 + t] = f2bf(o);
}

__global__ void k_out(const float* __restrict__ x, void* __restrict__ out, const int* __restrict__ dflag)
{
  int isbf = *dflag;
  int i = blockIdx.x*256 + threadIdx.x;
  if (isbf) ((u16*)out)[i] = f2bf(x[i]);
  else      ((float*)out)[i] = x[i];
}

extern "C" void kernel_launch(void* const* d_in, const int* in_sizes, int n_in,
                              void* d_out, int out_size, void* d_ws, size_t ws_size,
                              hipStream_t stream)
{
  const void* node_feats = d_in[0];
  const int*  edge_index = (const int*)d_in[1];
  const void* edge_attr  = d_in[2];
  const void* init_node_w= d_in[3];
  const void* init_edge_w= d_in[4];
  const void* lin_l_w    = d_in[5];
  const void* lin_l_b    = d_in[6];
  const void* lin_r_w    = d_in[7];
  const void* lin_r_b    = d_in[8];
  const void* lin_edge_w = d_in[9];
  const void* att        = d_in[10];
  const void* gat_bias   = d_in[11];
  const void* ln1_g      = d_in[12];
  const void* ln1_b      = d_in[13];
  const void* mlp_w1     = d_in[14];
  const void* mlp_w2     = d_in[15];
  const void* ln2_g      = d_in[16];
  const void* ln2_b      = d_in[17];

  const int* srcp = edge_index;
  const int* dstp = edge_index + EE;

  char* p = (char*)d_ws;
  auto alloc = [&](size_t bytes) { void* r = (void*)p; p += (bytes + 255) & ~(size_t)255; return r; };
  int*   dflag   = (int*)alloc(256);
  int*   deg     = (int*)alloc((size_t)NN*4);
  int*   rowstart= (int*)alloc((size_t)(NN+1)*4);
  int*   fill    = (int*)alloc((size_t)NN*4);
  int*   csr     = (int*)alloc((size_t)ET*4);
  int*   srcc    = (int*)alloc((size_t)ET*4);
  int*   dstc    = (int*)alloc((size_t)ET*4);
  int*   selfp   = (int*)alloc((size_t)NN*4);
  u16*   Wcb     = (u16*)alloc((size_t)2*256*64*2);
  u16*   wall    = (u16*)alloc((size_t)983040*2);   // bf16 weight pool
  u16*   attr_csr= (u16*)alloc((size_t)ET*64*2);    // 35.6 MB, CSR-ordered bf16 edge attrs
  float* logits  = (float*)alloc((size_t)ET*8*4);           // 8.9 MB
  float* hbuf    = (float*)alloc((size_t)NN*256*4);         // 16 MB
  float* xbuf    = (float*)alloc((size_t)NN*256*4);         // 16 MB
  u16*   xbufb   = (u16*)alloc((size_t)NN*256*2);
  u16*   hbufb   = (u16*)alloc((size_t)NN*256*2);
  u16*   xlr     = (u16*)alloc((size_t)NN*512*2);  // PERMUTED cols: xl 0..255, xr 256..511
  u16*   nfb     = (u16*)logits;    // dead before logits/hbuf are written
  u16*   ymid    = xlr;             // [NN,512] bf16 alias (xlr dead at MLP time; linear layout)
  u16*   y2      = (u16*)d_out;     // bf16 scratch; final k_out overwrites

  u16* Wn = wall;                   // [256][768]

  hipMemsetAsync(deg,  0, (size_t)NN*4, stream);
  hipMemsetAsync(fill, 0, (size_t)NN*4, stream);

  k_detect <<<1, 256, 0, stream>>>(node_feats, dflag);

  k_count  <<<(ET+255)/256, 256, 0, stream>>>(dstp, deg);
  k_scan   <<<1, 256, 0, stream>>>(deg, rowstart);
  k_scatter<<<(ET+255)/256, 256, 0, stream>>>(srcp, dstp, rowstart, fill, csr, srcc, dstc, selfp);
  // edge-parallel attr reorder (convert), then sequential-segment mean into self slots
  k_acsr   <<<(ET*4)/256, 256, 0, stream>>>(csr, edge_attr, attr_csr, dflag);
  k_lmean  <<<NN/4, 256, 0, stream>>>(rowstart, selfp, attr_csr);

  k_wc     <<<128, 256, 0, stream>>>(lin_edge_w, init_edge_w, Wcb, dflag);
  k_wcvt   <<<480, 256, 0, stream>>>(lin_l_w, lin_r_w, mlp_w1, mlp_w2, init_node_w, wall, dflag);

  // node_feats -> bf16
  k_cvt<<<(NN*768)/(8*256), 256, 0, stream>>>(node_feats, nfb, dflag);
  // x = node_feats @ init_node_w.T  (fp32 xbuf + bf16 xbufb)
  mg4<768,1,0,2,0><<<dim3(4, NN/64), 256, 0, stream>>>(nfb, Wn, nullptr, nullptr, 0, 1<<29, 0,
                                                       xbuf, xbufb, 256, dflag);

  for (int l = 0; l < 2; ++l) {
    size_t bo = (size_t)l*256;
    u16* Wlr = wall + 196608 + (size_t)l*393216;   // [512][256]: rows 0-255 lin_l, 256-511 lin_r
    u16* W1  = Wlr + 131072;                       // [512][256]
    u16* W2  = Wlr + 262144;                       // [256][512]
    // xlr = [x@Wl^T + bl | x@Wr^T + br]  (PERMUTED column layout)
    mg4<256,2,0,1,1><<<dim3(4, NN/64), 256, 0, stream>>>(xbufb, Wlr, lin_l_b, lin_r_b, bo, 256, 1,
                                                         xlr, nullptr, 512, dflag);
    k_elogits<<<1024, 256, 0, stream>>>(srcc, dstc, Wcb + (size_t)l*256*64, xlr,
                                        attr_csr, att, (size_t)l*256, logits, dflag);
    k_aggln  <<<NN/4, 256, 0, stream>>>(srcc, rowstart, logits, xlr, xbuf,
                                        gat_bias, ln1_g, ln1_b, bo, hbuf, hbufb, dflag);
    mg4<256,2,1,1,0><<<dim3(4, NN/64), 256, 0, stream>>>(hbufb, W1, nullptr, nullptr, 0, 1<<29, 0,
                                                         ymid, nullptr, 512, dflag);
    mg4<512,1,0,1,0><<<dim3(4, NN/64), 256, 0, stream>>>(ymid, W2, nullptr, nullptr, 0, 1<<29, 0,
                                                         y2, nullptr, 256, dflag);
    k_ln_add<<<NN, 256, 0, stream>>>(hbuf, y2, ln2_g, ln2_b, bo, xbuf, xbufb, dflag);
  }

  k_out<<<(NN*256)/256, 256, 0, stream>>>(xbuf, d_out, dflag);
}